// Round 6
// baseline (659.192 us; speedup 1.0000x reference)
//
#include <hip/hip_runtime.h>
#include <hip/hip_bf16.h>
#include <math.h>

#define NNODES 50000
#define NEDGES 800000
#define FIN 128
#define FH 256
#define NG 64
#define NC 64
#define SCAN_NB ((NNODES + 255) / 256)

typedef unsigned short bhalf;
typedef __attribute__((ext_vector_type(8))) short bf16x8;
typedef __attribute__((ext_vector_type(4))) float f32x4;

__device__ inline bhalf f2bf_rn(float f) {
    unsigned int u = __float_as_uint(f);
    u += 0x7FFFu + ((u >> 16) & 1u);      // round-to-nearest-even
    return (bhalf)(u >> 16);
}
__device__ inline float bf2f(bhalf h) { return __uint_as_float(((unsigned int)h) << 16); }
__device__ inline float2 bfpair(unsigned int u) {   // [lo16, hi16] -> two floats
    return make_float2(__uint_as_float(u << 16), __uint_as_float(u & 0xFFFF0000u));
}

// ---------------- degree / norm ----------------

__global__ void degree_kernel(const int* __restrict__ dst, int* __restrict__ degi, int E) {
    int e = blockIdx.x * blockDim.x + threadIdx.x;
    if (e < E) atomicAdd(&degi[dst[e]], 1);
}

__global__ void dinv_kernel(const int* __restrict__ degi, float* __restrict__ dinv, int Nn) {
    int n = blockIdx.x * blockDim.x + threadIdx.x;
    if (n < Nn) dinv[n] = rsqrtf((float)degi[n] + 1.0f);
}

// ---------------- per-graph node counts via binary search (batch is sorted) ----------------

__global__ __launch_bounds__(64)
void graph_bounds_kernel(const int* __restrict__ batch, float* __restrict__ cnt) {
    int g = threadIdx.x;
    int lo = 0, hi = NNODES;
    while (lo < hi) { int mid = (lo + hi) >> 1; if (batch[mid] < g) lo = mid + 1; else hi = mid; }
    int a = lo;
    lo = 0; hi = NNODES;
    while (lo < hi) { int mid = (lo + hi) >> 1; if (batch[mid] < g + 1) lo = mid + 1; else hi = mid; }
    cnt[g] = (float)(lo - a);
}

// ---------------- 2-level exclusive scan over degi -> row_start ----------------

__global__ __launch_bounds__(256)
void scan_block_kernel(const int* __restrict__ degi, int* __restrict__ local_ex,
                       int* __restrict__ partial, int Nn) {
    __shared__ int s[256];
    int i = blockIdx.x * 256 + threadIdx.x;
    int v = (i < Nn) ? degi[i] : 0;
    s[threadIdx.x] = v;
    __syncthreads();
#pragma unroll
    for (int off = 1; off < 256; off <<= 1) {
        int t = (threadIdx.x >= off) ? s[threadIdx.x - off] : 0;
        __syncthreads();
        s[threadIdx.x] += t;
        __syncthreads();
    }
    if (i < Nn) local_ex[i] = s[threadIdx.x] - v;
    if (threadIdx.x == 255) partial[blockIdx.x] = s[255];
}

__global__ __launch_bounds__(256)
void scan_partial_kernel(int* __restrict__ partial, int nb) {
    __shared__ int s[256];
    int v = (threadIdx.x < nb) ? partial[threadIdx.x] : 0;
    s[threadIdx.x] = v;
    __syncthreads();
#pragma unroll
    for (int off = 1; off < 256; off <<= 1) {
        int t = (threadIdx.x >= off) ? s[threadIdx.x - off] : 0;
        __syncthreads();
        s[threadIdx.x] += t;
        __syncthreads();
    }
    if (threadIdx.x < nb) partial[threadIdx.x] = s[threadIdx.x] - v;
}

__global__ void add_offsets_kernel(int* __restrict__ row_start, const int* __restrict__ local_ex,
                                   const int* __restrict__ partial, int Nn) {
    int i = blockIdx.x * 256 + threadIdx.x;
    if (i < Nn) row_start[i] = local_ex[i] + partial[blockIdx.x];
}

// ---------------- edge placement: CSR by dst, with precomputed edge norm ----------------

__global__ void edge_place_kernel(const int* __restrict__ src, const int* __restrict__ dst,
                                  const int* __restrict__ row_start, int* __restrict__ cursor,
                                  const float* __restrict__ dinv,
                                  int* __restrict__ esrc, float* __restrict__ enorm, int E) {
    int e = blockIdx.x * blockDim.x + threadIdx.x;
    if (e >= E) return;
    int s = src[e], d = dst[e];
    int pos = row_start[d] + atomicAdd(&cursor[d], 1);
    esrc[pos] = s;
    enorm[pos] = dinv[s] * dinv[d];
}

// ---------------- x -> bf16 copy (vectorized: 4 elems/thread) ----------------

__global__ void split_x_kernel(const float* __restrict__ x, bhalf* __restrict__ xb, int total4) {
    int i = blockIdx.x * blockDim.x + threadIdx.x;
    if (i >= total4) return;
    float4 v = *reinterpret_cast<const float4*>(&x[i * 4]);
    ushort4 o = {f2bf_rn(v.x), f2bf_rn(v.y), f2bf_rn(v.z), f2bf_rn(v.w)};
    *reinterpret_cast<ushort4*>(&xb[i * 4]) = o;
}

// ---------------- weight round+transpose: W[K][256] f32 -> Wt [256][K] bf16 ----------------

__global__ void split_w_kernel(const float* __restrict__ W, bhalf* __restrict__ Wt, int K) {
    int idx = blockIdx.x * 256 + threadIdx.x;
    if (idx >= K * 256) return;
    int k = idx >> 8, n = idx & 255;
    Wt[n * K + k] = f2bf_rn(W[idx]);
}

// ---------------- XCD-sliced CSR gather, 128 bf16 feats ----------------
// grid (8, nodeBlocks): blockIdx.x = column slice (16 bf16 cols = 32 B), fastest-varying
// so round-robin workgroup->XCD dispatch pins slice s to XCD s (3.2/2=1.6 MB slice fits L2).
// wave = 1 node: 8 edge-subgroups x 8 feature lanes; butterfly-reduce subgroups.

__global__ __launch_bounds__(256)
void gather128_kernel(const bhalf* __restrict__ xb, const int* __restrict__ esrc,
                      const float* __restrict__ enorm, const int* __restrict__ row_start,
                      const int* __restrict__ degi, const float* __restrict__ dinv,
                      bhalf* __restrict__ z, int Nn) {
    int slice = blockIdx.x;                       // 0..7
    int node = blockIdx.y * 4 + (threadIdx.x >> 6);
    if (node >= Nn) return;
    int lane = threadIdx.x & 63;
    int sub = lane >> 3;                          // 0..7 edge subgroup
    int f   = lane & 7;                           // uint index within slice (2 bf16 each)
    int coff = slice * 16 + f * 2;                // bhalf offset within row
    int st = row_start[node];
    int cnt = degi[node];
    float ax = 0.0f, ay = 0.0f;
    for (int j = sub; j < cnt; j += 8) {
        int   s0 = esrc[st + j];
        float n0 = enorm[st + j];
        float2 v = bfpair(*reinterpret_cast<const unsigned int*>(&xb[(size_t)s0 * FIN + coff]));
        ax += v.x * n0;
        ay += v.y * n0;
    }
#pragma unroll
    for (int m = 8; m < 64; m <<= 1) {
        ax += __shfl_xor(ax, m, 64);
        ay += __shfl_xor(ay, m, 64);
    }
    if (sub == 0) {
        float sn = dinv[node];
        sn *= sn;
        float2 xv = bfpair(*reinterpret_cast<const unsigned int*>(&xb[(size_t)node * FIN + coff]));
        ushort2 o = {f2bf_rn(ax + xv.x * sn), f2bf_rn(ay + xv.y * sn)};
        *reinterpret_cast<ushort2*>(&z[(size_t)node * FIN + coff]) = o;
    }
}

// ---------------- MFMA bf16 GEMM: C[M][256] = A[M][Kp] @ Bt[256][Kp]^T, bf16 out ----------------
// mode 1: C = bf16(gelu(acc + bias)).  mode 0: C = bf16(acc).

__global__ __launch_bounds__(256)
void gemm_mfma_kernel(const bhalf* __restrict__ A, const bhalf* __restrict__ Bt,
                      const float* __restrict__ bias, bhalf* __restrict__ C,
                      int M, int Kp, int mode) {
    __shared__ bhalf As[128 * 72];   // rows x (64+8 pad): 144 B row stride (16B-aligned)
    __shared__ bhalf Bs[128 * 72];
    const int tid  = threadIdx.x;
    const int lane = tid & 63;
    const int wave = tid >> 6;
    const int quad = lane >> 4;
    const int l15  = lane & 15;
    const int wm = (wave & 1) * 64;
    const int wn = (wave >> 1) * 64;
    const int bm = blockIdx.x * 128;
    const int bn = blockIdx.y * 128;

    f32x4 acc[4][4] = {};

    for (int k0 = 0; k0 < Kp; k0 += 64) {
#pragma unroll
        for (int i = 0; i < 4; i++) {
            int chunk = tid + i * 256;           // 1024 chunks of 8 bf16
            int r = chunk >> 3, c16 = chunk & 7;
            int gm = bm + r;
            float4 va = make_float4(0.f, 0.f, 0.f, 0.f);
            if (gm < M) va = *reinterpret_cast<const float4*>(&A[(size_t)gm * Kp + k0 + c16 * 8]);
            *reinterpret_cast<float4*>(&As[r * 72 + c16 * 8]) = va;
            float4 vb = *reinterpret_cast<const float4*>(&Bt[(size_t)(bn + r) * Kp + k0 + c16 * 8]);
            *reinterpret_cast<float4*>(&Bs[r * 72 + c16 * 8]) = vb;
        }
        __syncthreads();
#pragma unroll
        for (int kk = 0; kk < 64; kk += 32) {
            bf16x8 af[4], bfr[4];
#pragma unroll
            for (int mi = 0; mi < 4; mi++)
                af[mi] = *reinterpret_cast<const bf16x8*>(&As[(wm + mi * 16 + l15) * 72 + kk + quad * 8]);
#pragma unroll
            for (int ni = 0; ni < 4; ni++)
                bfr[ni] = *reinterpret_cast<const bf16x8*>(&Bs[(wn + ni * 16 + l15) * 72 + kk + quad * 8]);
#pragma unroll
            for (int mi = 0; mi < 4; mi++)
#pragma unroll
                for (int ni = 0; ni < 4; ni++)
                    acc[mi][ni] = __builtin_amdgcn_mfma_f32_16x16x32_bf16(af[mi], bfr[ni], acc[mi][ni], 0, 0, 0);
        }
        __syncthreads();
    }

    // epilogue: C/D layout col = lane&15, row = quad*4 + reg
#pragma unroll
    for (int mi = 0; mi < 4; mi++) {
#pragma unroll
        for (int r = 0; r < 4; r++) {
            int row = bm + wm + mi * 16 + quad * 4 + r;
            if (row >= M) continue;
#pragma unroll
            for (int ni = 0; ni < 4; ni++) {
                int col = bn + wn + ni * 16 + l15;
                float v = acc[mi][ni][r];
                if (mode == 1) {
                    v += bias[col];
                    v = 0.5f * v * (1.0f + erff(v * 0.70710678118654752f));
                }
                C[(size_t)row * FH + col] = f2bf_rn(v);
            }
        }
    }
}

// ---------------- XCD-sliced CSR gather, 256 bf16 feats -> h2 f32 ----------------
// blockIdx.x = column slice (32 bf16 cols = 64 B). Per-XCD t2 slice = 3.2 MB (fits 4 MB L2).
// wave = 1 node: 4 edge-subgroups x 16 feature lanes.

__global__ __launch_bounds__(256)
void gather256_kernel(const bhalf* __restrict__ t, const int* __restrict__ esrc,
                      const float* __restrict__ enorm, const int* __restrict__ row_start,
                      const int* __restrict__ degi, const float* __restrict__ dinv,
                      const float* __restrict__ bias, float* __restrict__ h, int Nn) {
    int slice = blockIdx.x;                       // 0..7
    int node = blockIdx.y * 4 + (threadIdx.x >> 6);
    if (node >= Nn) return;
    int lane = threadIdx.x & 63;
    int sub = lane >> 4;                          // 0..3 edge subgroup
    int f   = lane & 15;                          // uint index within slice (2 bf16 each)
    int coff = slice * 32 + f * 2;                // bhalf offset within row
    int st = row_start[node];
    int cnt = degi[node];
    float ax = 0.0f, ay = 0.0f;
    for (int j = sub; j < cnt; j += 4) {
        int   s0 = esrc[st + j];
        float n0 = enorm[st + j];
        float2 v = bfpair(*reinterpret_cast<const unsigned int*>(&t[(size_t)s0 * FH + coff]));
        ax += v.x * n0;
        ay += v.y * n0;
    }
#pragma unroll
    for (int m = 16; m < 64; m <<= 1) {
        ax += __shfl_xor(ax, m, 64);
        ay += __shfl_xor(ay, m, 64);
    }
    if (sub == 0) {
        float sn = dinv[node];
        sn *= sn;
        float2 tv = bfpair(*reinterpret_cast<const unsigned int*>(&t[(size_t)node * FH + coff]));
        float2 bv = *reinterpret_cast<const float2*>(&bias[coff]);
        float2 o = {ax + tv.x * sn + bv.x, ay + tv.y * sn + bv.y};
        *reinterpret_cast<float2*>(&h[(size_t)node * FH + coff]) = o;
    }
}

// ---------------- mean-pool (batch sorted) ----------------

__global__ __launch_bounds__(256)
void pool_kernel(const float* __restrict__ h, const int* __restrict__ batch,
                 float* __restrict__ pooled, int Nn, int npb) {
    int c = threadIdx.x;
    int n0 = blockIdx.x * npb;
    int n1 = min(n0 + npb, Nn);
    if (n0 >= n1) return;
    float acc = 0.0f;
    int cur = batch[n0];
    for (int n = n0; n < n1; n++) {
        int g = batch[n];
        if (g != cur) {
            atomicAdd(&pooled[cur * FH + c], acc);
            acc = 0.0f;
            cur = g;
        }
        acc += h[(size_t)n * FH + c];
    }
    atomicAdd(&pooled[cur * FH + c], acc);
}

// ---------------- FC head ----------------

__global__ __launch_bounds__(64)
void fc_kernel(const float* __restrict__ pooled, const float* __restrict__ cnt,
               const float* __restrict__ Wfc, const float* __restrict__ bfc,
               float* __restrict__ out) {
    int g = blockIdx.x;
    int c2 = threadIdx.x;
    float inv = 1.0f / fmaxf(cnt[g], 1.0f);
    float acc = 0.0f;
    for (int c = 0; c < FH; c++)
        acc += pooled[g * FH + c] * Wfc[c * NC + c2];
    out[g * NC + c2] = acc * inv + bfc[c2];
}

// ---------------- launch ----------------

extern "C" void kernel_launch(void* const* d_in, const int* in_sizes, int n_in,
                              void* d_out, int out_size, void* d_ws, size_t ws_size,
                              hipStream_t stream) {
    const float* x    = (const float*)d_in[0];
    const int*   ei   = (const int*)d_in[1];
    const int*   batch= (const int*)d_in[2];
    const float* W1   = (const float*)d_in[3];
    const float* b1   = (const float*)d_in[4];
    const float* W2   = (const float*)d_in[5];
    const float* b2   = (const float*)d_in[6];
    const float* Wfc  = (const float*)d_in[7];
    const float* bfc  = (const float*)d_in[8];
    float* out = (float*)d_out;

    const int* src = ei;
    const int* dst = ei + NEDGES;

    // workspace (~111 MB), heavy aliasing on stream order:
    // bufT [N,256]f32: xb[N,128]bf16 + z[N,128]bf16 early; t2[N,256]bf16 later (xb,z dead)
    // bufA [N,256]f32: h1[N,256]bf16 (first half) early; h2[N,256]f32 later (h1 dead)
    float* bufT     = (float*)d_ws;
    float* bufA     = bufT + (size_t)NNODES * FH;
    int*   esrc     = (int*)(bufA + (size_t)NNODES * FH);  // [E]
    float* enorm    = (float*)(esrc + NEDGES);             // [E]
    int*   degi     = (int*)(enorm + NEDGES);              // [N]
    int*   row_start= degi + NNODES;                       // [N]
    int*   local_ex = row_start + NNODES;                  // [N]
    int*   cursor   = local_ex + NNODES;                   // [N]
    int*   partial  = cursor + NNODES;                     // [256]
    float* dinv     = (float*)(partial + 256);             // [N]
    float* cnt      = dinv + NNODES;                       // [G]
    float* pooled   = cnt + NG;                            // [G,256]
    bhalf* w1t      = (bhalf*)(pooled + NG * FH);          // [256,128]
    bhalf* w2t      = w1t + 256 * FIN;                     // [256,256]

    bhalf* xb = (bhalf*)bufT;                              // [N,128] bf16
    bhalf* zb = xb + (size_t)NNODES * FIN;                 // [N,128] bf16
    bhalf* t2 = (bhalf*)bufT;                              // [N,256] bf16 (overlays xb+zb)
    bhalf* h1 = (bhalf*)bufA;                              // [N,256] bf16
    float* h2 = bufA;                                      // [N,256] f32 (overlays h1)

    hipMemsetAsync(degi,   0, NNODES * sizeof(int), stream);
    hipMemsetAsync(cursor, 0, NNODES * sizeof(int), stream);
    hipMemsetAsync(pooled, 0, NG * FH * sizeof(float), stream);

    // ---- CSR build + norms ----
    degree_kernel<<<(NEDGES + 255) / 256, 256, 0, stream>>>(dst, degi, NEDGES);
    graph_bounds_kernel<<<1, 64, 0, stream>>>(batch, cnt);
    dinv_kernel<<<(NNODES + 255) / 256, 256, 0, stream>>>(degi, dinv, NNODES);
    scan_block_kernel<<<SCAN_NB, 256, 0, stream>>>(degi, local_ex, partial, NNODES);
    scan_partial_kernel<<<1, 256, 0, stream>>>(partial, SCAN_NB);
    add_offsets_kernel<<<SCAN_NB, 256, 0, stream>>>(row_start, local_ex, partial, NNODES);
    edge_place_kernel<<<(NEDGES + 255) / 256, 256, 0, stream>>>(src, dst, row_start, cursor,
                                                                dinv, esrc, enorm, NEDGES);

    // ---- bf16 conversions (tiny) ----
    split_x_kernel<<<(NNODES * FIN / 4 + 255) / 256, 256, 0, stream>>>(x, xb, NNODES * FIN / 4);
    split_w_kernel<<<(FIN * 256 + 255) / 256, 256, 0, stream>>>(W1, w1t, FIN);
    split_w_kernel<<<(FH  * 256 + 255) / 256, 256, 0, stream>>>(W2, w2t, FH);

    dim3 sgrid(8, (NNODES + 3) / 4);               // slice fastest-varying -> XCD pinning
    dim3 mgrid((NNODES + 127) / 128, 2);

    // conv1 (aggregate-first): z = bf16(Ahat*x) ; h1 = bf16(gelu(z@W1 + b1))
    gather128_kernel<<<sgrid, 256, 0, stream>>>(xb, esrc, enorm, row_start, degi,
                                                dinv, zb, NNODES);
    gemm_mfma_kernel<<<mgrid, 256, 0, stream>>>(zb, w1t, b1, h1, NNODES, FIN, 1);

    // conv2 (transform-first): t2 = bf16(h1@W2) ; h2 = Ahat*t2 + b2 (f32)
    gemm_mfma_kernel<<<mgrid, 256, 0, stream>>>(h1, w2t, b2, t2, NNODES, FH, 0);
    gather256_kernel<<<sgrid, 256, 0, stream>>>(t2, esrc, enorm, row_start, degi,
                                                dinv, b2, h2, NNODES);

    // mean-pool + FC head
    pool_kernel<<<(NNODES + 63) / 64, 256, 0, stream>>>(h2, batch, pooled, NNODES, 64);
    fc_kernel<<<NG, NC, 0, stream>>>(pooled, cnt, Wfc, bfc, out);
}

// Round 9
// 375.367 us; speedup vs baseline: 1.7561x; 1.7561x over previous
//
#include <hip/hip_runtime.h>
#include <hip/hip_bf16.h>
#include <hip/hip_fp16.h>
#include <math.h>

#define NNODES 50000
#define NEDGES 800000
#define FIN 128
#define FH 256
#define NG 64
#define NC 64
#define SCAN_NB ((NNODES + 255) / 256)

typedef unsigned short bhalf;
typedef __attribute__((ext_vector_type(8))) short bf16x8;
typedef __attribute__((ext_vector_type(4))) float f32x4;
typedef __attribute__((ext_vector_type(4))) unsigned short u16x4;

__device__ inline bhalf f2bf_rn(float f) {
    unsigned int u = __float_as_uint(f);
    u += 0x7FFFu + ((u >> 16) & 1u);      // round-to-nearest-even
    return (bhalf)(u >> 16);
}
__device__ inline float bf2f(bhalf h) { return __uint_as_float(((unsigned int)h) << 16); }
__device__ inline float2 bfpair(unsigned int u) {   // [lo16, hi16] -> two floats
    return make_float2(__uint_as_float(u << 16), __uint_as_float(u & 0xFFFF0000u));
}
__device__ inline float edec_norm(unsigned int ed) {  // low 16 bits = f16 norm
    return __half2float(__ushort_as_half((unsigned short)(ed & 0xFFFFu)));
}

// ---------------- degree ----------------

__global__ void degree_kernel(const int* __restrict__ dst, int* __restrict__ degi, int E) {
    int e = blockIdx.x * blockDim.x + threadIdx.x;
    if (e < E) atomicAdd(&degi[dst[e]], 1);
}

// ---------------- 2-level exclusive scan over degi -> row_start (+ fused dinv) ----------------

__global__ __launch_bounds__(256)
void scan_block_kernel(const int* __restrict__ degi, int* __restrict__ local_ex,
                       int* __restrict__ partial, float* __restrict__ dinv, int Nn) {
    __shared__ int s[256];
    int i = blockIdx.x * 256 + threadIdx.x;
    int v = (i < Nn) ? degi[i] : 0;
    s[threadIdx.x] = v;
    __syncthreads();
#pragma unroll
    for (int off = 1; off < 256; off <<= 1) {
        int t = (threadIdx.x >= off) ? s[threadIdx.x - off] : 0;
        __syncthreads();
        s[threadIdx.x] += t;
        __syncthreads();
    }
    if (i < Nn) {
        local_ex[i] = s[threadIdx.x] - v;
        dinv[i] = rsqrtf((float)v + 1.0f);
    }
    if (threadIdx.x == 255) partial[blockIdx.x] = s[255];
}

__global__ __launch_bounds__(256)
void scan_partial_kernel(int* __restrict__ partial, int nb) {
    __shared__ int s[256];
    int v = (threadIdx.x < nb) ? partial[threadIdx.x] : 0;
    s[threadIdx.x] = v;
    __syncthreads();
#pragma unroll
    for (int off = 1; off < 256; off <<= 1) {
        int t = (threadIdx.x >= off) ? s[threadIdx.x - off] : 0;
        __syncthreads();
        s[threadIdx.x] += t;
        __syncthreads();
    }
    if (threadIdx.x < nb) partial[threadIdx.x] = s[threadIdx.x] - v;
}

__global__ void add_offsets_kernel(int* __restrict__ row_start, const int* __restrict__ local_ex,
                                   const int* __restrict__ partial, int Nn) {
    int i = blockIdx.x * 256 + threadIdx.x;
    if (i < Nn) row_start[i] = local_ex[i] + partial[blockIdx.x];
}

// ---------------- edge placement: CSR by dst, packed (src:u16 | f16 norm) ----------------

__global__ void edge_place_kernel(const int* __restrict__ src, const int* __restrict__ dst,
                                  const int* __restrict__ row_start, int* __restrict__ cursor,
                                  const float* __restrict__ dinv,
                                  unsigned int* __restrict__ edata, int E) {
    int e = blockIdx.x * blockDim.x + threadIdx.x;
    if (e >= E) return;
    int s = src[e], d = dst[e];
    int pos = row_start[d] + atomicAdd(&cursor[d], 1);
    float nm = dinv[s] * dinv[d];
    unsigned short hb = __half_as_ushort(__float2half(nm));
    edata[pos] = ((unsigned int)s << 16) | (unsigned int)hb;
}

// ---------------- x -> bf16 copy ----------------

__global__ void split_x_kernel(const float* __restrict__ x, bhalf* __restrict__ xb, int total4) {
    int i = blockIdx.x * blockDim.x + threadIdx.x;
    if (i >= total4) return;
    float4 v = *reinterpret_cast<const float4*>(&x[i * 4]);
    u16x4 o = {f2bf_rn(v.x), f2bf_rn(v.y), f2bf_rn(v.z), f2bf_rn(v.w)};
    *reinterpret_cast<u16x4*>(&xb[i * 4]) = o;
}

// ---------------- weight round+transpose: W[K][256] f32 -> Wt [256][K] bf16 ----------------

__global__ void split_w_kernel(const float* __restrict__ W, bhalf* __restrict__ Wt, int K) {
    int idx = blockIdx.x * 256 + threadIdx.x;
    if (idx >= K * 256) return;
    int k = idx >> 8, n = idx & 255;
    Wt[n * K + k] = f2bf_rn(W[idx]);
}

// ---------------- CSR gather, 128 bf16 feats: z[n] = bf16(sum + x[n]*sn), unroll-4 ----------------

__global__ __launch_bounds__(256)
void gather128_kernel(const bhalf* __restrict__ xb, const unsigned int* __restrict__ edata,
                      const int* __restrict__ row_start, const int* __restrict__ degi,
                      const float* __restrict__ dinv, bhalf* __restrict__ z, int Nn) {
    int node = blockIdx.x * 4 + (threadIdx.x >> 6);
    if (node >= Nn) return;
    int lane = threadIdx.x & 63;
    int st = row_start[node];
    int cnt = degi[node];
    float ax = 0.0f, ay = 0.0f;
    int j = 0;
    for (; j + 3 < cnt; j += 4) {
        unsigned int e0 = edata[st + j],     e1 = edata[st + j + 1];
        unsigned int e2 = edata[st + j + 2], e3 = edata[st + j + 3];
        float2 v0 = bfpair(*reinterpret_cast<const unsigned int*>(&xb[(size_t)(e0 >> 16) * FIN + lane * 2]));
        float2 v1 = bfpair(*reinterpret_cast<const unsigned int*>(&xb[(size_t)(e1 >> 16) * FIN + lane * 2]));
        float2 v2 = bfpair(*reinterpret_cast<const unsigned int*>(&xb[(size_t)(e2 >> 16) * FIN + lane * 2]));
        float2 v3 = bfpair(*reinterpret_cast<const unsigned int*>(&xb[(size_t)(e3 >> 16) * FIN + lane * 2]));
        float n0 = edec_norm(e0), n1 = edec_norm(e1), n2 = edec_norm(e2), n3 = edec_norm(e3);
        ax += v0.x * n0 + v1.x * n1 + v2.x * n2 + v3.x * n3;
        ay += v0.y * n0 + v1.y * n1 + v2.y * n2 + v3.y * n3;
    }
    for (; j < cnt; j++) {
        unsigned int e0 = edata[st + j];
        float2 v0 = bfpair(*reinterpret_cast<const unsigned int*>(&xb[(size_t)(e0 >> 16) * FIN + lane * 2]));
        float n0 = edec_norm(e0);
        ax += v0.x * n0; ay += v0.y * n0;
    }
    float sn = dinv[node];
    sn *= sn;
    float2 xv = bfpair(*reinterpret_cast<const unsigned int*>(&xb[(size_t)node * FIN + lane * 2]));
    ushort2 o = {f2bf_rn(ax + xv.x * sn), f2bf_rn(ay + xv.y * sn)};
    *reinterpret_cast<ushort2*>(&z[(size_t)node * FIN + lane * 2]) = o;
}

// ---------------- MFMA bf16 GEMM: C[M][256] = A[M][Kp] @ Bt[256][Kp]^T, bf16 out ----------------
// mode 1: C = bf16(gelu(acc + bias)).  mode 0: C = bf16(acc).

__global__ __launch_bounds__(256)
void gemm_mfma_kernel(const bhalf* __restrict__ A, const bhalf* __restrict__ Bt,
                      const float* __restrict__ bias, bhalf* __restrict__ C,
                      int M, int Kp, int mode) {
    __shared__ bhalf As[128 * 72];   // rows x (64+8 pad): 144 B row stride (16B-aligned)
    __shared__ bhalf Bs[128 * 72];
    const int tid  = threadIdx.x;
    const int lane = tid & 63;
    const int wave = tid >> 6;
    const int quad = lane >> 4;
    const int l15  = lane & 15;
    const int wm = (wave & 1) * 64;
    const int wn = (wave >> 1) * 64;
    const int bm = blockIdx.x * 128;
    const int bn = blockIdx.y * 128;

    f32x4 acc[4][4] = {};

    for (int k0 = 0; k0 < Kp; k0 += 64) {
#pragma unroll
        for (int i = 0; i < 4; i++) {
            int chunk = tid + i * 256;           // 1024 chunks of 8 bf16
            int r = chunk >> 3, c16 = chunk & 7;
            int gm = bm + r;
            float4 va = make_float4(0.f, 0.f, 0.f, 0.f);
            if (gm < M) va = *reinterpret_cast<const float4*>(&A[(size_t)gm * Kp + k0 + c16 * 8]);
            *reinterpret_cast<float4*>(&As[r * 72 + c16 * 8]) = va;
            float4 vb = *reinterpret_cast<const float4*>(&Bt[(size_t)(bn + r) * Kp + k0 + c16 * 8]);
            *reinterpret_cast<float4*>(&Bs[r * 72 + c16 * 8]) = vb;
        }
        __syncthreads();
#pragma unroll
        for (int kk = 0; kk < 64; kk += 32) {
            bf16x8 af[4], bfr[4];
#pragma unroll
            for (int mi = 0; mi < 4; mi++)
                af[mi] = *reinterpret_cast<const bf16x8*>(&As[(wm + mi * 16 + l15) * 72 + kk + quad * 8]);
#pragma unroll
            for (int ni = 0; ni < 4; ni++)
                bfr[ni] = *reinterpret_cast<const bf16x8*>(&Bs[(wn + ni * 16 + l15) * 72 + kk + quad * 8]);
#pragma unroll
            for (int mi = 0; mi < 4; mi++)
#pragma unroll
                for (int ni = 0; ni < 4; ni++)
                    acc[mi][ni] = __builtin_amdgcn_mfma_f32_16x16x32_bf16(af[mi], bfr[ni], acc[mi][ni], 0, 0, 0);
        }
        __syncthreads();
    }

    // epilogue: C/D layout col = lane&15, row = quad*4 + reg
#pragma unroll
    for (int mi = 0; mi < 4; mi++) {
#pragma unroll
        for (int r = 0; r < 4; r++) {
            int row = bm + wm + mi * 16 + quad * 4 + r;
            if (row >= M) continue;
#pragma unroll
            for (int ni = 0; ni < 4; ni++) {
                int col = bn + wn + ni * 16 + l15;
                float v = acc[mi][ni][r];
                if (mode == 1) {
                    v += bias[col];
                    v = 0.5f * v * (1.0f + erff(v * 0.70710678118654752f));
                }
                C[(size_t)row * FH + col] = f2bf_rn(v);
            }
        }
    }
}

// ---------------- CSR gather, 256 bf16 feats + self + bias -> h2 f32, unroll-4 ----------------

__global__ __launch_bounds__(256)
void gather256_kernel(const bhalf* __restrict__ t, const unsigned int* __restrict__ edata,
                      const int* __restrict__ row_start, const int* __restrict__ degi,
                      const float* __restrict__ dinv, const float* __restrict__ bias,
                      float* __restrict__ h, int Nn) {
    int node = blockIdx.x * 4 + (threadIdx.x >> 6);
    if (node >= Nn) return;
    int lane = threadIdx.x & 63;
    int st = row_start[node];
    int cnt = degi[node];
    float a0 = 0.f, a1 = 0.f, a2 = 0.f, a3 = 0.f;
    int j = 0;
    for (; j + 3 < cnt; j += 4) {
        unsigned int e0 = edata[st + j],     e1 = edata[st + j + 1];
        unsigned int e2 = edata[st + j + 2], e3 = edata[st + j + 3];
        uint2 u0 = *reinterpret_cast<const uint2*>(&t[(size_t)(e0 >> 16) * FH + lane * 4]);
        uint2 u1 = *reinterpret_cast<const uint2*>(&t[(size_t)(e1 >> 16) * FH + lane * 4]);
        uint2 u2 = *reinterpret_cast<const uint2*>(&t[(size_t)(e2 >> 16) * FH + lane * 4]);
        uint2 u3 = *reinterpret_cast<const uint2*>(&t[(size_t)(e3 >> 16) * FH + lane * 4]);
        float n0 = edec_norm(e0), n1 = edec_norm(e1), n2 = edec_norm(e2), n3 = edec_norm(e3);
        float2 p;
        p = bfpair(u0.x); a0 += p.x * n0; a1 += p.y * n0;
        p = bfpair(u0.y); a2 += p.x * n0; a3 += p.y * n0;
        p = bfpair(u1.x); a0 += p.x * n1; a1 += p.y * n1;
        p = bfpair(u1.y); a2 += p.x * n1; a3 += p.y * n1;
        p = bfpair(u2.x); a0 += p.x * n2; a1 += p.y * n2;
        p = bfpair(u2.y); a2 += p.x * n2; a3 += p.y * n2;
        p = bfpair(u3.x); a0 += p.x * n3; a1 += p.y * n3;
        p = bfpair(u3.y); a2 += p.x * n3; a3 += p.y * n3;
    }
    for (; j < cnt; j++) {
        unsigned int e0 = edata[st + j];
        uint2 u0 = *reinterpret_cast<const uint2*>(&t[(size_t)(e0 >> 16) * FH + lane * 4]);
        float n0 = edec_norm(e0);
        float2 p;
        p = bfpair(u0.x); a0 += p.x * n0; a1 += p.y * n0;
        p = bfpair(u0.y); a2 += p.x * n0; a3 += p.y * n0;
    }
    float sn = dinv[node];
    sn *= sn;
    uint2 uv = *reinterpret_cast<const uint2*>(&t[(size_t)node * FH + lane * 4]);
    float2 ta = bfpair(uv.x), tb = bfpair(uv.y);
    float4 bv = *reinterpret_cast<const float4*>(&bias[lane * 4]);
    float4 o = {a0 + ta.x * sn + bv.x, a1 + ta.y * sn + bv.y,
                a2 + tb.x * sn + bv.z, a3 + tb.y * sn + bv.w};
    *reinterpret_cast<float4*>(&h[(size_t)node * FH + lane * 4]) = o;
}

// ---------------- mean-pool (batch sorted) ----------------

__global__ __launch_bounds__(256)
void pool_kernel(const float* __restrict__ h, const int* __restrict__ batch,
                 float* __restrict__ pooled, int Nn, int npb) {
    int c = threadIdx.x;
    int n0 = blockIdx.x * npb;
    int n1 = min(n0 + npb, Nn);
    if (n0 >= n1) return;
    float acc = 0.0f;
    int cur = batch[n0];
    for (int n = n0; n < n1; n++) {
        int g = batch[n];
        if (g != cur) {
            atomicAdd(&pooled[cur * FH + c], acc);
            acc = 0.0f;
            cur = g;
        }
        acc += h[(size_t)n * FH + c];
    }
    atomicAdd(&pooled[cur * FH + c], acc);
}

// ---------------- FC head (graph bounds inlined: batch is sorted) ----------------

__global__ __launch_bounds__(64)
void fc_kernel(const float* __restrict__ pooled, const int* __restrict__ batch,
               const float* __restrict__ Wfc, const float* __restrict__ bfc,
               float* __restrict__ out) {
    int g = blockIdx.x;
    int c2 = threadIdx.x;
    int lo = 0, hi = NNODES;
    while (lo < hi) { int m = (lo + hi) >> 1; if (batch[m] < g) lo = m + 1; else hi = m; }
    int a = lo;
    lo = 0; hi = NNODES;
    while (lo < hi) { int m = (lo + hi) >> 1; if (batch[m] < g + 1) lo = m + 1; else hi = m; }
    float inv = 1.0f / fmaxf((float)(lo - a), 1.0f);
    float acc = 0.0f;
    for (int c = 0; c < FH; c++)
        acc += pooled[g * FH + c] * Wfc[c * NC + c2];
    out[g * NC + c2] = acc * inv + bfc[c2];
}

// ---------------- launch ----------------

extern "C" void kernel_launch(void* const* d_in, const int* in_sizes, int n_in,
                              void* d_out, int out_size, void* d_ws, size_t ws_size,
                              hipStream_t stream) {
    const float* x    = (const float*)d_in[0];
    const int*   ei   = (const int*)d_in[1];
    const int*   batch= (const int*)d_in[2];
    const float* W1   = (const float*)d_in[3];
    const float* b1   = (const float*)d_in[4];
    const float* W2   = (const float*)d_in[5];
    const float* b2   = (const float*)d_in[6];
    const float* Wfc  = (const float*)d_in[7];
    const float* bfc  = (const float*)d_in[8];
    float* out = (float*)d_out;

    const int* src = ei;
    const int* dst = ei + NEDGES;

    // workspace (~107 MB). Aliasing on stream order:
    // bufT: xb[N,128]bf16 + zb[N,128]bf16 early; t2[N,256]bf16 later (xb,zb dead)
    // bufA: h1[N,256]bf16 early; h2[N,256]f32 later (h1 dead)
    float* bufT      = (float*)d_ws;
    float* bufA      = bufT + (size_t)NNODES * FH;
    unsigned int* edata = (unsigned int*)(bufA + (size_t)NNODES * FH);  // [E] packed
    int*   row_start = (int*)(edata + NEDGES);             // [N]
    int*   local_ex  = row_start + NNODES;                 // [N]
    int*   partial   = local_ex + NNODES;                  // [256]
    float* dinv      = (float*)(partial + 256);            // [N]
    bhalf* w1t       = (bhalf*)(dinv + NNODES);            // [256,128]
    bhalf* w2t       = w1t + 256 * FIN;                    // [256,256]
    // ---- contiguous zeroed region ----
    int*   degi      = (int*)(w2t + 256 * FH);             // [N]
    int*   cursor    = degi + NNODES;                      // [N]
    float* pooled    = (float*)(cursor + NNODES);          // [G,256]
    size_t zero_bytes = (size_t)(2 * NNODES + NG * FH) * 4;

    bhalf* xb = (bhalf*)bufT;                              // [N,128] bf16
    bhalf* zb = xb + (size_t)NNODES * FIN;                 // [N,128] bf16
    bhalf* t2 = (bhalf*)bufT;                              // [N,256] bf16 (overlays xb+zb)
    bhalf* h1 = (bhalf*)bufA;                              // [N,256] bf16
    float* h2 = bufA;                                      // [N,256] f32 (overlays h1)

    (void)hipMemsetAsync(degi, 0, zero_bytes, stream);

    // ---- CSR build + norms ----
    degree_kernel<<<(NEDGES + 255) / 256, 256, 0, stream>>>(dst, degi, NEDGES);
    scan_block_kernel<<<SCAN_NB, 256, 0, stream>>>(degi, local_ex, partial, dinv, NNODES);
    scan_partial_kernel<<<1, 256, 0, stream>>>(partial, SCAN_NB);
    add_offsets_kernel<<<SCAN_NB, 256, 0, stream>>>(row_start, local_ex, partial, NNODES);
    edge_place_kernel<<<(NEDGES + 255) / 256, 256, 0, stream>>>(src, dst, row_start, cursor,
                                                                dinv, edata, NEDGES);

    // ---- bf16 conversions ----
    split_x_kernel<<<(NNODES * FIN / 4 + 255) / 256, 256, 0, stream>>>(x, xb, NNODES * FIN / 4);
    split_w_kernel<<<(FIN * 256 + 255) / 256, 256, 0, stream>>>(W1, w1t, FIN);
    split_w_kernel<<<(FH  * 256 + 255) / 256, 256, 0, stream>>>(W2, w2t, FH);

    int gather_blocks = (NNODES + 3) / 4;
    dim3 mgrid((NNODES + 127) / 128, 2);

    // conv1 (aggregate-first): z = bf16(Ahat*x) ; h1 = bf16(gelu(z@W1 + b1))
    gather128_kernel<<<gather_blocks, 256, 0, stream>>>(xb, edata, row_start, degi,
                                                        dinv, zb, NNODES);
    gemm_mfma_kernel<<<mgrid, 256, 0, stream>>>(zb, w1t, b1, h1, NNODES, FIN, 1);

    // conv2 (transform-first): t2 = bf16(h1@W2) ; h2 = Ahat*t2 + b2 (f32)
    gemm_mfma_kernel<<<mgrid, 256, 0, stream>>>(h1, w2t, b2, t2, NNODES, FH, 0);
    gather256_kernel<<<gather_blocks, 256, 0, stream>>>(t2, edata, row_start, degi,
                                                        dinv, b2, h2, NNODES);

    // mean-pool + FC head
    pool_kernel<<<(NNODES + 63) / 64, 256, 0, stream>>>(h2, batch, pooled, NNODES, 64);
    fc_kernel<<<NG, NC, 0, stream>>>(pooled, batch, Wfc, bfc, out);
}